// Round 13
// baseline (879.777 us; speedup 1.0000x reference)
//
#include <hip/hip_runtime.h>
#include <hip/hip_bf16.h>
#include <math.h>

static constexpr int BROWS = 16384;
static constexpr int IND   = 128;
static constexpr int DE    = 512;
static constexpr int DOUTD = 256;
static constexpr int ED    = 64;
static constexpr int NE    = 1024;

static constexpr size_t O_XHAT = 1;
static constexpr size_t O_PERP = 2097153;
static constexpr size_t O_ZQ   = 2097154;
static constexpr size_t O_IDX  = 6291458;

typedef __attribute__((ext_vector_type(8))) short short8v;
typedef __attribute__((ext_vector_type(4))) float f32x4;
typedef __attribute__((ext_vector_type(4))) unsigned short ushort4v;
typedef __attribute__((ext_vector_type(8))) unsigned short ushort8v;

__device__ inline float wave_sum(float v) {
#pragma unroll
    for (int o = 32; o >= 1; o >>= 1) v += __shfl_xor(v, o, 64);
    return v;
}

__device__ inline unsigned short f2bf(float f) {
    unsigned u = __float_as_uint(f);
    return (unsigned short)((u + 0x7FFFu + ((u >> 16) & 1u)) >> 16);
}
__device__ inline float bf2f(unsigned short b) {
    return __uint_as_float(((unsigned)b) << 16);
}
struct Split3 { unsigned short b0, b1, b2; };
__device__ inline Split3 split3(float v) {
    Split3 s;
    s.b0 = f2bf(v);  float r  = v - bf2f(s.b0);
    s.b1 = f2bf(r);  float r2 = r - bf2f(s.b1);
    s.b2 = f2bf(r2);
    return s;
}

// ---------------- 8-term split-bf16 MFMA GEMM core (proven idx-exact class) -------------
// LDS: [128][32] shorts per plane, granule-swizzled (g' = g ^ ((row>>1)&3)) -> 48 KB total,
// 3 blocks/CU (was 60 KB padded, 2 blocks/CU). Bank profile 2-way (free) on reads+writes.
template<int K, int EPI>
__device__ inline void gemm8_body(const unsigned short* __restrict__ A0, const unsigned short* __restrict__ A1,
                                  const unsigned short* __restrict__ A2,
                                  const unsigned short* __restrict__ W0, const unsigned short* __restrict__ W1,
                                  const unsigned short* __restrict__ W2,
                                  const float* __restrict__ bias, float* __restrict__ Cf,
                                  unsigned short* __restrict__ S0, unsigned short* __restrict__ S1,
                                  unsigned short* __restrict__ S2, int N,
                                  short (*As)[128 * 32], short (*Ws)[128 * 32])
{
    const int t = threadIdx.x;
    const int bm = blockIdx.x << 7, bn = blockIdx.y << 7;   // x = M (fast), y = N
    const int lane = t & 63, wid = t >> 6;
    const int wm = (wid >> 1) << 6, wn = (wid & 1) << 6;
    const int lr = lane & 15, lg = lane >> 4;
    const unsigned short* Ap[3] = {A0, A1, A2};
    const unsigned short* Wp[3] = {W0, W1, W2};
    f32x4 acc[4][4] = {};
    for (int k0 = 0; k0 < K; k0 += 32) {
#pragma unroll
        for (int p = 0; p < 3; ++p) {
#pragma unroll
            for (int s = 0; s < 2; ++s) {
                int c = t + (s << 8);
                int row = c >> 2, g = c & 3;
                int gs = g ^ ((row >> 1) & 3);
                *(short8v*)&As[p][row * 32 + (gs << 3)] =
                    *(const short8v*)(Ap[p] + (size_t)(bm + row) * K + k0 + (g << 3));
                *(short8v*)&Ws[p][row * 32 + (gs << 3)] =
                    *(const short8v*)(Wp[p] + (size_t)(bn + row) * K + k0 + (g << 3));
            }
        }
        __syncthreads();
        short8v bfr[3][4];
#pragma unroll
        for (int nj = 0; nj < 4; ++nj) {
            int row = wn + nj * 16 + lr;
            int gs = lg ^ ((row >> 1) & 3);
#pragma unroll
            for (int p = 0; p < 3; ++p)
                bfr[p][nj] = *(const short8v*)&Ws[p][row * 32 + (gs << 3)];
        }
#pragma unroll
        for (int mi = 0; mi < 4; ++mi) {
            int arow = wm + mi * 16 + lr;
            int ags = lg ^ ((arow >> 1) & 3);
            short8v a0 = *(const short8v*)&As[0][arow * 32 + (ags << 3)];
            short8v a1 = *(const short8v*)&As[1][arow * 32 + (ags << 3)];
            short8v a2 = *(const short8v*)&As[2][arow * 32 + (ags << 3)];
#pragma unroll
            for (int nj = 0; nj < 4; ++nj) {
                f32x4 c = acc[mi][nj];
                c = __builtin_amdgcn_mfma_f32_16x16x32_bf16(a2, bfr[1][nj], c, 0, 0, 0);
                c = __builtin_amdgcn_mfma_f32_16x16x32_bf16(a1, bfr[2][nj], c, 0, 0, 0);
                c = __builtin_amdgcn_mfma_f32_16x16x32_bf16(a1, bfr[1][nj], c, 0, 0, 0);
                c = __builtin_amdgcn_mfma_f32_16x16x32_bf16(a2, bfr[0][nj], c, 0, 0, 0);
                c = __builtin_amdgcn_mfma_f32_16x16x32_bf16(a0, bfr[2][nj], c, 0, 0, 0);
                c = __builtin_amdgcn_mfma_f32_16x16x32_bf16(a1, bfr[0][nj], c, 0, 0, 0);
                c = __builtin_amdgcn_mfma_f32_16x16x32_bf16(a0, bfr[1][nj], c, 0, 0, 0);
                c = __builtin_amdgcn_mfma_f32_16x16x32_bf16(a0, bfr[0][nj], c, 0, 0, 0);
                acc[mi][nj] = c;
            }
        }
        __syncthreads();
    }
#pragma unroll
    for (int mi = 0; mi < 4; ++mi)
#pragma unroll
        for (int nj = 0; nj < 4; ++nj)
#pragma unroll
            for (int r = 0; r < 4; ++r) {
                int m = bm + wm + mi * 16 + lg * 4 + r;
                int n = bn + wn + nj * 16 + lr;
                float v = acc[mi][nj][r] + bias[n];
                if (EPI == 0) {
                    Cf[(size_t)m * N + n] = v;
                } else {
                    Split3 sp = split3(v);
                    S0[(size_t)m * N + n] = sp.b0;
                    S1[(size_t)m * N + n] = sp.b1;
                    S2[(size_t)m * N + n] = sp.b2;
                }
            }
}

template<int K>
__global__ __launch_bounds__(256, 3)
void gemm8_k(const unsigned short* __restrict__ A0, const unsigned short* __restrict__ A1,
             const unsigned short* __restrict__ A2,
             const unsigned short* __restrict__ W0, const unsigned short* __restrict__ W1,
             const unsigned short* __restrict__ W2,
             const float* __restrict__ bias, float* __restrict__ C, int N)
{
    __shared__ short As[3][128 * 32];
    __shared__ short Ws[3][128 * 32];
    gemm8_body<K, 0>(A0, A1, A2, W0, W1, W2, bias, C, nullptr, nullptr, nullptr, N, As, Ws);
}

struct G8 { const unsigned short *A0, *A1, *A2, *W0, *W1, *W2; const float* bias;
            float* Cf; unsigned short *S0, *S1, *S2; };

template<int K, int EPI>
__global__ __launch_bounds__(256, 3)
void gemm8pair_k(G8 ga, G8 gb, int N)
{
    __shared__ short As[3][128 * 32];
    __shared__ short Ws[3][128 * 32];
    const G8& g = (blockIdx.z == 0) ? ga : gb;
    gemm8_body<K, EPI>(g.A0, g.A1, g.A2, g.W0, g.W1, g.W2, g.bias, g.Cf,
                       g.S0, g.S1, g.S2, N, As, Ws);
}

// ---------------- bf16 MFMA GEMM (decoder): C = A@W^T + bias ----------------------------
template<int K, int EPI>
__global__ __launch_bounds__(256)
void gemmbf_k(const short* __restrict__ A, const short* __restrict__ W,
              const float* __restrict__ bias, float* __restrict__ C, int N,
              unsigned short* __restrict__ Cb,
              const float* __restrict__ escale, const float* __restrict__ eshift)
{
    __shared__ short As[128 * 40];
    __shared__ short Ws[128 * 40];
    const int t = threadIdx.x;
    const int bm = blockIdx.x << 7, bn = blockIdx.y << 7;   // x = M (fast)
    const int lane = t & 63, wid = t >> 6;
    const int wm = (wid >> 1) << 6, wn = (wid & 1) << 6;
    const int lr = lane & 15, lg = lane >> 4;
    f32x4 acc[4][4] = {};
    for (int k0 = 0; k0 < K; k0 += 32) {
#pragma unroll
        for (int s = 0; s < 2; ++s) {
            int c = t + (s << 8);
            int row = c >> 2, kc = (c & 3) << 3;
            *(short8v*)&As[row * 40 + kc] = *(const short8v*)(A + (size_t)(bm + row) * K + k0 + kc);
            *(short8v*)&Ws[row * 40 + kc] = *(const short8v*)(W + (size_t)(bn + row) * K + k0 + kc);
        }
        __syncthreads();
        short8v af[4], bf[4];
#pragma unroll
        for (int mi = 0; mi < 4; ++mi) af[mi] = *(const short8v*)&As[(wm + mi * 16 + lr) * 40 + lg * 8];
#pragma unroll
        for (int nj = 0; nj < 4; ++nj) bf[nj] = *(const short8v*)&Ws[(wn + nj * 16 + lr) * 40 + lg * 8];
#pragma unroll
        for (int mi = 0; mi < 4; ++mi)
#pragma unroll
            for (int nj = 0; nj < 4; ++nj)
                acc[mi][nj] = __builtin_amdgcn_mfma_f32_16x16x32_bf16(af[mi], bf[nj], acc[mi][nj], 0, 0, 0);
        __syncthreads();
    }
#pragma unroll
    for (int mi = 0; mi < 4; ++mi)
#pragma unroll
        for (int nj = 0; nj < 4; ++nj)
#pragma unroll
            for (int r = 0; r < 4; ++r) {
                int m = bm + wm + mi * 16 + lg * 4 + r;
                int n = bn + wn + nj * 16 + lr;
                float v = acc[mi][nj][r] + bias[n];
                if (EPI == 2) v = escale[n] * v + eshift[n];
                C[(size_t)m * N + n] = v;
                if (EPI == 1) Cb[(size_t)m * N + n] = f2bf(v);
            }
}

// -------------- merged preprocessing: weight splits, input splits, c2/cbS ---------------
__global__ __launch_bounds__(256)
void pre_k(const float* __restrict__ x, const float* __restrict__ scale,
           const float* __restrict__ shift,
           unsigned short* __restrict__ x0, unsigned short* __restrict__ x1,
           unsigned short* __restrict__ x2,
           const float* __restrict__ a,
           unsigned short* __restrict__ a0, unsigned short* __restrict__ a1,
           unsigned short* __restrict__ a2,
           const float* __restrict__ ain_w, const float* __restrict__ win_w,
           const float* __restrict__ ares_w, const float* __restrict__ wres_w,
           const float* __restrict__ out_w, unsigned short* __restrict__ wsb,
           const float* __restrict__ cb, float* __restrict__ c2, int* __restrict__ counts,
           unsigned short* __restrict__ cbS0, unsigned short* __restrict__ cbS1,
           unsigned short* __restrict__ cbS2)
{
    const int b = blockIdx.x;
    const int t = threadIdx.x;
    if (b < 768) {
        int g4 = b * 256 + t;
        const float* src; unsigned short *d0, *d1, *d2; int base;
        if (g4 < 16384)       { src = ain_w;  d0 = wsb;           d1 = wsb + 65536;   d2 = wsb + 131072;  base = 0; }
        else if (g4 < 32768)  { src = win_w;  d0 = wsb + 196608;  d1 = wsb + 262144;  d2 = wsb + 327680;  base = 16384; }
        else if (g4 < 98304)  { src = ares_w; d0 = wsb + 393216;  d1 = wsb + 655360;  d2 = wsb + 917504;  base = 32768; }
        else if (g4 < 163840) { src = wres_w; d0 = wsb + 1179648; d1 = wsb + 1441792; d2 = wsb + 1703936; base = 98304; }
        else                  { src = out_w;  d0 = wsb + 1966080; d1 = wsb + 2097152; d2 = wsb + 2228224; base = 163840; }
        int l4 = g4 - base;
        float4 v = *(const float4*)(src + (size_t)l4 * 4);
        float vals[4] = {v.x, v.y, v.z, v.w};
        ushort4v o0, o1, o2;
#pragma unroll
        for (int i = 0; i < 4; ++i) {
            Split3 s = split3(vals[i]);
            o0[i] = s.b0; o1[i] = s.b1; o2[i] = s.b2;
        }
        *(ushort4v*)(d0 + (size_t)l4 * 4) = o0;
        *(ushort4v*)(d1 + (size_t)l4 * 4) = o1;
        *(ushort4v*)(d2 + (size_t)l4 * 4) = o2;
    } else if (b < 4864) {
        int bb = b - 768;
        if (bb < 2048) {
            int g = bb * 256 + t;
            float4 v = *(const float4*)(x + (size_t)g * 4);
            int col = (g * 4) & (IND - 1);
            float vals[4] = {v.x, v.y, v.z, v.w};
            ushort4v o0, o1, o2;
#pragma unroll
            for (int i = 0; i < 4; ++i) {
                float xs = (vals[i] - shift[col + i]) / scale[col + i];
                Split3 s = split3(xs);
                o0[i] = s.b0; o1[i] = s.b1; o2[i] = s.b2;
            }
            *(ushort4v*)(x0 + (size_t)g * 4) = o0;
            *(ushort4v*)(x1 + (size_t)g * 4) = o1;
            *(ushort4v*)(x2 + (size_t)g * 4) = o2;
        } else {
            int g = (bb - 2048) * 256 + t;
            float4 v = *(const float4*)(a + (size_t)g * 4);
            float vals[4] = {v.x, v.y, v.z, v.w};
            ushort4v o0, o1, o2;
#pragma unroll
            for (int i = 0; i < 4; ++i) {
                Split3 s = split3(vals[i]);
                o0[i] = s.b0; o1[i] = s.b1; o2[i] = s.b2;
            }
            *(ushort4v*)(a0 + (size_t)g * 4) = o0;
            *(ushort4v*)(a1 + (size_t)g * 4) = o1;
            *(ushort4v*)(a2 + (size_t)g * 4) = o2;
        }
    } else {
        int j = (b - 4864) * 256 + t;
        if (j < NE) {
            float s = 0.f;
            const float* p = cb + (size_t)j * ED;
#pragma unroll
            for (int d = 0; d < ED; ++d) s = fmaf(p[d], p[d], s);
            c2[j] = s;
            counts[j] = 0;
#pragma unroll
            for (int dc = 0; dc < 64; dc += 4) {
                float4 v = *(const float4*)(p + dc);
                float vals[4] = {v.x, v.y, v.z, v.w};
                ushort4v o0, o1, o2;
#pragma unroll
                for (int i = 0; i < 4; ++i) {
                    Split3 sp = split3(vals[i]);
                    o0[i] = sp.b0; o1[i] = sp.b1; o2[i] = sp.b2;
                }
                *(ushort4v*)(cbS0 + (size_t)j * 64 + dc) = o0;
                *(ushort4v*)(cbS1 + (size_t)j * 64 + dc) = o1;
                *(ushort4v*)(cbS2 + (size_t)j * 64 + dc) = o2;
            }
        }
    }
}

// -------------- decoder weight cvts (runs AFTER encoder: w1b aliases avS0) --------------
__global__ __launch_bounds__(256)
void cvt3_k(const float* __restrict__ dec1_w, const float* __restrict__ dres_w,
            const float* __restrict__ dec2_w,
            unsigned short* __restrict__ w1b, unsigned short* __restrict__ wrb,
            unsigned short* __restrict__ w2b)
{
    int g = blockIdx.x * 256 + threadIdx.x;
    if (g < 131072)       w1b[g] = f2bf(dec1_w[g]);
    else if (g < 393216)  wrb[g - 131072] = f2bf(dres_w[g - 131072]);
    else if (g < 458752)  w2b[g - 393216] = f2bf(dec2_w[g - 393216]);
}

// -------------- fused encoder resblock tail on split state ------------------------------
__global__ __launch_bounds__(256)
void ln_enc2s_k(const float* __restrict__ T1, const float* __restrict__ T2,
                unsigned short* __restrict__ a0, unsigned short* __restrict__ a1,
                unsigned short* __restrict__ a2,
                unsigned short* __restrict__ h0, unsigned short* __restrict__ h1,
                unsigned short* __restrict__ h2,
                const float* __restrict__ ag, const float* __restrict__ abe,
                const float* __restrict__ wg, const float* __restrict__ wbe)
{
    const int lane = threadIdx.x & 63;
    const int row  = (blockIdx.x << 2) + (threadIdx.x >> 6);
    const int col  = lane << 3;
    const size_t base = (size_t)row * DE + col;
    float t[8];
    { float4 p0 = *(const float4*)(T1 + base); float4 p1 = *(const float4*)(T1 + base + 4);
      t[0]=p0.x; t[1]=p0.y; t[2]=p0.z; t[3]=p0.w; t[4]=p1.x; t[5]=p1.y; t[6]=p1.z; t[7]=p1.w; }
    float s = 0.f;
#pragma unroll
    for (int i = 0; i < 8; ++i) s += t[i];
    s = wave_sum(s);
    float mean = s * (1.0f / 512.0f);
    float vs = 0.f;
#pragma unroll
    for (int i = 0; i < 8; ++i) { float d = t[i] - mean; vs += d * d; }
    vs = wave_sum(vs);
    float rstd = 1.0f / sqrtf(vs * (1.0f / 512.0f) + 1e-5f);
    float avn[8];
    {
        ushort8v b0 = *(const ushort8v*)(a0 + base);
        ushort8v b1 = *(const ushort8v*)(a1 + base);
        ushort8v b2 = *(const ushort8v*)(a2 + base);
        ushort8v o0, o1, o2;
#pragma unroll
        for (int i = 0; i < 8; ++i) {
            float avv = bf2f(b0[i]) + bf2f(b1[i]) + bf2f(b2[i]);
            float lnv = (t[i] - mean) * rstd * ag[col + i] + abe[col + i];
            avn[i] = avv + fmaxf(lnv, 0.0f);
            Split3 sp = split3(avn[i]);
            o0[i] = sp.b0; o1[i] = sp.b1; o2[i] = sp.b2;
        }
        *(ushort8v*)(a0 + base) = o0;
        *(ushort8v*)(a1 + base) = o1;
        *(ushort8v*)(a2 + base) = o2;
    }
    { float4 p0 = *(const float4*)(T2 + base); float4 p1 = *(const float4*)(T2 + base + 4);
      t[0]=p0.x; t[1]=p0.y; t[2]=p0.z; t[3]=p0.w; t[4]=p1.x; t[5]=p1.y; t[6]=p1.z; t[7]=p1.w; }
    s = 0.f;
#pragma unroll
    for (int i = 0; i < 8; ++i) s += t[i];
    s = wave_sum(s);
    float mean2 = s * (1.0f / 512.0f);
    vs = 0.f;
#pragma unroll
    for (int i = 0; i < 8; ++i) { float d = t[i] - mean2; vs += d * d; }
    vs = wave_sum(vs);
    float rstd2 = 1.0f / sqrtf(vs * (1.0f / 512.0f) + 1e-5f);
    {
        ushort8v b0 = *(const ushort8v*)(h0 + base);
        ushort8v b1 = *(const ushort8v*)(h1 + base);
        ushort8v b2 = *(const ushort8v*)(h2 + base);
        ushort8v o0, o1, o2;
#pragma unroll
        for (int i = 0; i < 8; ++i) {
            float hv  = bf2f(b0[i]) + bf2f(b1[i]) + bf2f(b2[i]);
            float lnv = (t[i] - mean2) * rstd2 * wg[col + i] + wbe[col + i];
            float hn  = (hv + fmaxf(lnv, 0.0f)) * avn[i];
            Split3 sp = split3(hn);
            o0[i] = sp.b0; o1[i] = sp.b1; o2[i] = sp.b2;
        }
        *(ushort8v*)(h0 + base) = o0;
        *(ushort8v*)(h1 + base) = o1;
        *(ushort8v*)(h2 + base) = o2;
    }
}

// -------------- decoder resblock tail ---------------------------------------------------
__global__ __launch_bounds__(256)
void ln_dec_k(const float* __restrict__ t_, float* __restrict__ h,
              const float* __restrict__ g, const float* __restrict__ be,
              unsigned short* __restrict__ hb)
{
    const int lane = threadIdx.x & 63;
    const int row  = (blockIdx.x << 2) + (threadIdx.x >> 6);
    const int col  = lane << 3;
    const size_t base = (size_t)row * DE + col;
    float t[8];
    { float4 p0 = *(const float4*)(t_ + base); float4 p1 = *(const float4*)(t_ + base + 4);
      t[0]=p0.x; t[1]=p0.y; t[2]=p0.z; t[3]=p0.w; t[4]=p1.x; t[5]=p1.y; t[6]=p1.z; t[7]=p1.w; }
    float s = 0.f;
#pragma unroll
    for (int i = 0; i < 8; ++i) s += t[i];
    s = wave_sum(s);
    float mean = s * (1.0f / 512.0f);
    float vs = 0.f;
#pragma unroll
    for (int i = 0; i < 8; ++i) { float d = t[i] - mean; vs += d * d; }
    vs = wave_sum(vs);
    float rstd = 1.0f / sqrtf(vs * (1.0f / 512.0f) + 1e-5f);
    float4 p0 = *(const float4*)(h + base); float4 p1 = *(const float4*)(h + base + 4);
    float hv[8] = {p0.x,p0.y,p0.z,p0.w,p1.x,p1.y,p1.z,p1.w};
    float hn[8];
    ushort8v ob;
#pragma unroll
    for (int i = 0; i < 8; ++i) {
        float lnv = (t[i] - mean) * rstd * g[col + i] + be[col + i];
        hn[i] = hv[i] + fmaxf(lnv, 0.0f);
        ob[i] = f2bf(hn[i]);
    }
    float4 o0 = {hn[0],hn[1],hn[2],hn[3]}, o1 = {hn[4],hn[5],hn[6],hn[7]};
    *(float4*)(h + base) = o0; *(float4*)(h + base + 4) = o1;
    *(ushort8v*)(hb + base) = ob;
}

// -------------- VQ v7: MFMA distances, double-buffered code tiles (T14 split) -----------
__global__ __launch_bounds__(256)
void vq_k(const float* __restrict__ ze, const float* __restrict__ cb, const float* __restrict__ c2,
          const unsigned short* __restrict__ cbS0, const unsigned short* __restrict__ cbS1,
          const unsigned short* __restrict__ cbS2,
          float* __restrict__ idx_dst, float* __restrict__ zst_dst,
          unsigned short* __restrict__ zb,
          int* __restrict__ counts, float* __restrict__ partials)
{
    __shared__ unsigned short P[2][3][64 * 64];
    __shared__ float z2s[64];
    __shared__ int   bidxs[64];
    __shared__ float red[4];
    const int t = threadIdx.x;
    const int lane = t & 63, w = t >> 6;
    const size_t row0 = (size_t)blockIdx.x * 64;

#pragma unroll
    for (int s = 0; s < 2; ++s) {
        int c = t + (s << 8);
        int row = c >> 3, kb = c & 7;
        float4 v0 = *(const float4*)(ze + (row0 + row) * 64 + kb * 8);
        float4 v1 = *(const float4*)(ze + (row0 + row) * 64 + kb * 8 + 4);
        float vals[8] = {v0.x, v0.y, v0.z, v0.w, v1.x, v1.y, v1.z, v1.w};
        ushort8v o0, o1, o2;
#pragma unroll
        for (int i = 0; i < 8; ++i) {
            Split3 sp = split3(vals[i]);
            o0[i] = sp.b0; o1[i] = sp.b1; o2[i] = sp.b2;
        }
        int base = row * 64 + ((kb ^ (row & 7)) << 3);
        *(ushort8v*)&P[1][0][base] = o0;
        *(ushort8v*)&P[1][1][base] = o1;
        *(ushort8v*)&P[1][2][base] = o2;
        int gbase = row * 64 + kb * 8;
        *(ushort8v*)&P[0][0][base] = *(const ushort8v*)(cbS0 + gbase);
        *(ushort8v*)&P[0][1][base] = *(const ushort8v*)(cbS1 + gbase);
        *(ushort8v*)&P[0][2][base] = *(const ushort8v*)(cbS2 + gbase);
    }
    if (t < 64) {
        float z2 = 0.f;
        const float* zp = ze + (row0 + t) * 64;
#pragma unroll 8
        for (int d = 0; d < 64; ++d) z2 = fmaf(zp[d], zp[d], z2);
        z2s[t] = z2;
    }
    __syncthreads();

    short8v af[2][3];
    {
        int row = (w << 4) + (lane & 15);
#pragma unroll
        for (int ks = 0; ks < 2; ++ks) {
            int kb = (lane >> 4) + ks * 4;
            int base = row * 64 + ((kb ^ (row & 7)) << 3);
#pragma unroll
            for (int p = 0; p < 3; ++p)
                af[ks][p] = *(const short8v*)&P[1][p][base];
        }
    }
    __syncthreads();

    float best[4] = {INFINITY, INFINITY, INFINITY, INFINITY};
    int   bid[4]  = {0, 0, 0, 0};
    for (int tt = 0; tt < 16; ++tt) {
        const int cur = tt & 1;
        ushort8v nx0[2], nx1[2], nx2[2];
        if (tt < 15) {
#pragma unroll
            for (int s = 0; s < 2; ++s) {
                int c = t + (s << 8);
                int code = c >> 3, kb = c & 7;
                size_t gbase = (size_t)((tt + 1) * 64 + code) * 64 + kb * 8;
                nx0[s] = *(const ushort8v*)(cbS0 + gbase);
                nx1[s] = *(const ushort8v*)(cbS1 + gbase);
                nx2[s] = *(const ushort8v*)(cbS2 + gbase);
            }
        }
        const int t0 = tt << 6;
#pragma unroll
        for (int ct = 0; ct < 4; ++ct) {
            f32x4 acc = {0.f, 0.f, 0.f, 0.f};
            int code = (ct << 4) + (lane & 15);
#pragma unroll
            for (int ks = 0; ks < 2; ++ks) {
                int kb = (lane >> 4) + ks * 4;
                int base = code * 64 + ((kb ^ (code & 7)) << 3);
                short8v b0 = *(const short8v*)&P[cur][0][base];
                short8v b1 = *(const short8v*)&P[cur][1][base];
                short8v b2 = *(const short8v*)&P[cur][2][base];
                acc = __builtin_amdgcn_mfma_f32_16x16x32_bf16(af[ks][2], b1, acc, 0, 0, 0);
                acc = __builtin_amdgcn_mfma_f32_16x16x32_bf16(af[ks][1], b2, acc, 0, 0, 0);
                acc = __builtin_amdgcn_mfma_f32_16x16x32_bf16(af[ks][1], b1, acc, 0, 0, 0);
                acc = __builtin_amdgcn_mfma_f32_16x16x32_bf16(af[ks][2], b0, acc, 0, 0, 0);
                acc = __builtin_amdgcn_mfma_f32_16x16x32_bf16(af[ks][0], b2, acc, 0, 0, 0);
                acc = __builtin_amdgcn_mfma_f32_16x16x32_bf16(af[ks][1], b0, acc, 0, 0, 0);
                acc = __builtin_amdgcn_mfma_f32_16x16x32_bf16(af[ks][0], b1, acc, 0, 0, 0);
                acc = __builtin_amdgcn_mfma_f32_16x16x32_bf16(af[ks][0], b0, acc, 0, 0, 0);
            }
            float c2v = c2[t0 + code];
            int gcode = t0 + code;
#pragma unroll
            for (int r = 0; r < 4; ++r) {
                float z2v = z2s[(w << 4) + ((lane >> 4) << 2) + r];
                float term = __fadd_rn(z2v, c2v);
                float dist = __fsub_rn(term, __fmul_rn(2.0f, acc[r]));
                if (dist < best[r]) { best[r] = dist; bid[r] = gcode; }
            }
        }
        if (tt < 15) {
#pragma unroll
            for (int s = 0; s < 2; ++s) {
                int c = t + (s << 8);
                int code = c >> 3, kb = c & 7;
                int base = code * 64 + ((kb ^ (code & 7)) << 3);
                *(ushort8v*)&P[cur ^ 1][0][base] = nx0[s];
                *(ushort8v*)&P[cur ^ 1][1][base] = nx1[s];
                *(ushort8v*)&P[cur ^ 1][2][base] = nx2[s];
            }
        }
        __syncthreads();
    }
#pragma unroll
    for (int r = 0; r < 4; ++r) {
        float bd = best[r]; int bi = bid[r];
#pragma unroll
        for (int m = 1; m < 16; m <<= 1) {
            float od = __shfl_xor(bd, m, 64);
            int   oi = __shfl_xor(bi, m, 64);
            if (od < bd || (od == bd && oi < bi)) { bd = od; bi = oi; }
        }
        if ((lane & 15) == 0) {
            int row = (w << 4) + ((lane >> 4) << 2) + r;
            bidxs[row] = bi;
            idx_dst[row0 + row] = (float)bi;
            atomicAdd(&counts[bi], 1);
        }
    }
    __syncthreads();
    const int row = t >> 2, cq = t & 3;
    const int bi = bidxs[row];
    float lsum = 0.f;
#pragma unroll
    for (int dd = 0; dd < 16; dd += 4) {
        int d0 = (cq << 4) + dd;
        float4 q4 = *(const float4*)(cb + (size_t)bi * 64 + d0);
        float qv[4] = {q4.x, q4.y, q4.z, q4.w};
        float4 zv4 = *(const float4*)(ze + (row0 + row) * 64 + d0);
        float zvv[4] = {zv4.x, zv4.y, zv4.z, zv4.w};
        float zst[4];
#pragma unroll
        for (int i = 0; i < 4; ++i) {
            float zv = zvv[i];
            float df = qv[i] - zv;
            lsum = fmaf(df, df, lsum);
            zst[i] = __fadd_rn(zv, __fsub_rn(qv[i], zv));
            zb[(row0 + row) * 64 + d0 + i] = f2bf(zst[i]);
        }
        float2 o0 = {zst[0], zst[1]}, o1 = {zst[2], zst[3]};
        *(float2*)(zst_dst + (row0 + row) * 64 + d0) = o0;
        *(float2*)(zst_dst + (row0 + row) * 64 + d0 + 2) = o1;
    }
    lsum = wave_sum(lsum);
    if ((t & 63) == 0) red[t >> 6] = lsum;
    __syncthreads();
    if (t == 0) partials[blockIdx.x] = ((red[0] + red[1]) + red[2]) + red[3];
}

// -------------- finalize: loss + perplexity ---------------------------------------------
__global__ __launch_bounds__(256)
void fin_k(const float* __restrict__ partials, const int* __restrict__ counts,
           float* __restrict__ loss_out, float* __restrict__ perp_out)
{
    __shared__ float red[4];
    __shared__ float red2[4];
    const int tid = threadIdx.x;
    float v = 0.f;
    for (int c = tid; c < 1024; c += 256) v += partials[c];
    float s = wave_sum(v);
    if ((tid & 63) == 0) red[tid >> 6] = s;
    float ep = 0.f;
    for (int c = tid; c < NE; c += 256) {
        float e = (float)counts[c] * (1.0f / 65536.0f);
        ep += e * logf(e + 1e-10f);
    }
    ep = wave_sum(ep);
    if ((tid & 63) == 0) red2[tid >> 6] = ep;
    __syncthreads();
    if (tid == 0) {
        float S = ((red[0] + red[1]) + red[2]) + red[3];
        float E = ((red2[0] + red2[1]) + red2[2]) + red2[3];
        loss_out[0] = 1.25f * (S * (1.0f / 4194304.0f));
        perp_out[0] = expf(-E);
    }
}

extern "C" void kernel_launch(void* const* d_in, const int* in_sizes, int n_in,
                              void* d_out, int out_size, void* d_ws, size_t ws_size,
                              hipStream_t stream)
{
    const float* x       = (const float*)d_in[0];
    const float* a       = (const float*)d_in[1];
    const float* scale   = (const float*)d_in[2];
    const float* shift   = (const float*)d_in[3];
    const float* win_w   = (const float*)d_in[4];
    const float* win_b   = (const float*)d_in[5];
    const float* ain_w   = (const float*)d_in[6];
    const float* ain_b   = (const float*)d_in[7];
    const float* wres_w  = (const float*)d_in[8];
    const float* wres_b  = (const float*)d_in[9];
    const float* wres_g  = (const float*)d_in[10];
    const float* wres_be = (const float*)d_in[11];
    const float* ares_w  = (const float*)d_in[12];
    const float* ares_b  = (const float*)d_in[13];
    const float* ares_g  = (const float*)d_in[14];
    const float* ares_be = (const float*)d_in[15];
    const float* out_w   = (const float*)d_in[16];
    const float* out_b   = (const float*)d_in[17];
    const float* dec1_w  = (const float*)d_in[18];
    const float* dec1_b  = (const float*)d_in[19];
    const float* dres_w  = (const float*)d_in[20];
    const float* dres_b  = (const float*)d_in[21];
    const float* dres_g  = (const float*)d_in[22];
    const float* dres_be = (const float*)d_in[23];
    const float* dec2_w  = (const float*)d_in[24];
    const float* dec2_b  = (const float*)d_in[25];
    const float* cb      = (const float*)d_in[26];

    float* ws = (float*)d_ws;
    unsigned short* u = (unsigned short*)d_ws;
    unsigned short* avS0 = u;
    unsigned short* avS1 = u + 8388608;
    unsigned short* avS2 = u + 16777216;
    unsigned short* hS0  = u + 25165824;
    unsigned short* hS1  = u + 33554432;
    unsigned short* hS2  = u + 41943040;
    float* T1 = ws + 25165824;
    float* T2 = ws + 29360128;
    float* ZE = ws + 25165824;
    unsigned short* aS0  = u + 50331648, *aS1  = u + 52428800, *aS2  = u + 54525952;
    unsigned short* xsS0 = u + 56623104, *xsS1 = u + 58720256, *xsS2 = u + 60817408;
    unsigned short* ZB  = u;
    unsigned short* w1b = u + 4194304;            // aliases avS0 upper half: written post-encoder only
    unsigned short* wrb = u + 4325376;
    unsigned short* w2b = u + 4587520;
    float* t_dec = ws + 4194304;
    float* hd    = ws + 12582912;
    unsigned short* Hb = (unsigned short*)(ws + 29360128);
    unsigned short* wsb = u + 67108864;
    unsigned short* ainS0 = wsb,            *ainS1 = wsb + 65536,  *ainS2 = wsb + 131072;
    unsigned short* winS0 = wsb + 196608,   *winS1 = wsb + 262144, *winS2 = wsb + 327680;
    unsigned short* areS0 = wsb + 393216,   *areS1 = wsb + 655360, *areS2 = wsb + 917504;
    unsigned short* wreS0 = wsb + 1179648,  *wreS1 = wsb + 1441792,*wreS2 = wsb + 1703936;
    unsigned short* outS0 = wsb + 1966080,  *outS1 = wsb + 2097152,*outS2 = wsb + 2228224;
    float* c2v      = ws + 34800000;
    int*   counts   = (int*)(ws + 34801024);
    float* partials = ws + 34802048;
    unsigned short* cbS0 = u + 69606144;
    unsigned short* cbS1 = u + 69671680;
    unsigned short* cbS2 = u + 69737216;

    float* dout = (float*)d_out;

    pre_k<<<4868, 256, 0, stream>>>(x, scale, shift, xsS0, xsS1, xsS2,
                                    a, aS0, aS1, aS2,
                                    ain_w, win_w, ares_w, wres_w, out_w, wsb,
                                    cb, c2v, counts, cbS0, cbS1, cbS2);
    {
        G8 ga = {aS0, aS1, aS2, ainS0, ainS1, ainS2, ain_b, nullptr, avS0, avS1, avS2};
        G8 gb = {xsS0, xsS1, xsS2, winS0, winS1, winS2, win_b, nullptr, hS0, hS1, hS2};
        gemm8pair_k<128, 1><<<dim3(128, 4, 2), 256, 0, stream>>>(ga, gb, DE);
    }
    for (int r = 0; r < 3; ++r) {
        for (int half = 0; half < 2; ++half) {
            const size_t mo = (size_t)half * 8192 * DE;
            G8 ga = {avS0 + mo, avS1 + mo, avS2 + mo, areS0, areS1, areS2, ares_b, T1, nullptr, nullptr, nullptr};
            G8 gb = {hS0 + mo,  hS1 + mo,  hS2 + mo,  wreS0, wreS1, wreS2, wres_b, T2, nullptr, nullptr, nullptr};
            gemm8pair_k<512, 0><<<dim3(64, 4, 2), 256, 0, stream>>>(ga, gb, DE);
            ln_enc2s_k<<<2048, 256, 0, stream>>>(T1, T2,
                avS0 + mo, avS1 + mo, avS2 + mo, hS0 + mo, hS1 + mo, hS2 + mo,
                ares_g, ares_be, wres_g, wres_be);
        }
    }
    gemm8_k<512><<<dim3(128, 2), 256, 0, stream>>>(hS0, hS1, hS2, outS0, outS1, outS2, out_b, ZE, DOUTD);
    cvt3_k<<<1792, 256, 0, stream>>>(dec1_w, dres_w, dec2_w, w1b, wrb, w2b);
    vq_k<<<1024, 256, 0, stream>>>(ZE, cb, c2v, cbS0, cbS1, cbS2,
                                   dout + O_IDX, dout + O_ZQ, ZB, counts, partials);
    fin_k<<<1, 256, 0, stream>>>(partials, counts, dout, dout + O_PERP);
    gemmbf_k<256, 1><<<dim3(128, 4), 256, 0, stream>>>(
        (const short*)ZB, (const short*)w1b, dec1_b, hd, DE, Hb, nullptr, nullptr);
    for (int r = 0; r < 3; ++r) {
        gemmbf_k<512, 0><<<dim3(128, 4), 256, 0, stream>>>(
            (const short*)Hb, (const short*)wrb, dres_b, t_dec, DE, nullptr, nullptr, nullptr);
        ln_dec_k<<<4096, 256, 0, stream>>>(t_dec, hd, dres_g, dres_be, Hb);
    }
    gemmbf_k<512, 2><<<dim3(128, 1), 256, 0, stream>>>(
        (const short*)Hb, (const short*)w2b, dec2_b, dout + O_XHAT, IND, nullptr, scale, shift);
}

// Round 14
// 789.169 us; speedup vs baseline: 1.1148x; 1.1148x over previous
//
#include <hip/hip_runtime.h>
#include <hip/hip_bf16.h>
#include <math.h>

static constexpr int BROWS = 16384;
static constexpr int IND   = 128;
static constexpr int DE    = 512;
static constexpr int DOUTD = 256;
static constexpr int ED    = 64;
static constexpr int NE    = 1024;

static constexpr size_t O_XHAT = 1;
static constexpr size_t O_PERP = 2097153;
static constexpr size_t O_ZQ   = 2097154;
static constexpr size_t O_IDX  = 6291458;

typedef __attribute__((ext_vector_type(8))) short short8v;
typedef __attribute__((ext_vector_type(4))) float f32x4;
typedef __attribute__((ext_vector_type(4))) unsigned short ushort4v;
typedef __attribute__((ext_vector_type(8))) unsigned short ushort8v;

__device__ inline float wave_sum(float v) {
#pragma unroll
    for (int o = 32; o >= 1; o >>= 1) v += __shfl_xor(v, o, 64);
    return v;
}

__device__ inline unsigned short f2bf(float f) {
    unsigned u = __float_as_uint(f);
    return (unsigned short)((u + 0x7FFFu + ((u >> 16) & 1u)) >> 16);
}
__device__ inline float bf2f(unsigned short b) {
    return __uint_as_float(((unsigned)b) << 16);
}
struct Split3 { unsigned short b0, b1, b2; };
__device__ inline Split3 split3(float v) {
    Split3 s;
    s.b0 = f2bf(v);  float r  = v - bf2f(s.b0);
    s.b1 = f2bf(r);  float r2 = r - bf2f(s.b1);
    s.b2 = f2bf(r2);
    return s;
}

// ---------------- 8-term split-bf16 MFMA GEMM core (round-12 proven, padded LDS) --------
template<int K, int EPI>
__device__ inline void gemm8_body(const unsigned short* __restrict__ A0, const unsigned short* __restrict__ A1,
                                  const unsigned short* __restrict__ A2,
                                  const unsigned short* __restrict__ W0, const unsigned short* __restrict__ W1,
                                  const unsigned short* __restrict__ W2,
                                  const float* __restrict__ bias, float* __restrict__ Cf,
                                  unsigned short* __restrict__ S0, unsigned short* __restrict__ S1,
                                  unsigned short* __restrict__ S2, int N,
                                  short (*As)[128 * 40], short (*Ws)[128 * 40])
{
    const int t = threadIdx.x;
    const int bm = blockIdx.x << 7, bn = blockIdx.y << 7;   // x = M (fast), y = N
    const int lane = t & 63, wid = t >> 6;
    const int wm = (wid >> 1) << 6, wn = (wid & 1) << 6;
    const int lr = lane & 15, lg = lane >> 4;
    const unsigned short* Ap[3] = {A0, A1, A2};
    const unsigned short* Wp[3] = {W0, W1, W2};
    f32x4 acc[4][4] = {};
    for (int k0 = 0; k0 < K; k0 += 32) {
#pragma unroll
        for (int p = 0; p < 3; ++p) {
#pragma unroll
            for (int s = 0; s < 2; ++s) {
                int c = t + (s << 8);
                int row = c >> 2, kc = (c & 3) << 3;
                *(short8v*)&As[p][row * 40 + kc] =
                    *(const short8v*)(Ap[p] + (size_t)(bm + row) * K + k0 + kc);
                *(short8v*)&Ws[p][row * 40 + kc] =
                    *(const short8v*)(Wp[p] + (size_t)(bn + row) * K + k0 + kc);
            }
        }
        __syncthreads();
        short8v bfr[3][4];
#pragma unroll
        for (int p = 0; p < 3; ++p)
#pragma unroll
            for (int nj = 0; nj < 4; ++nj)
                bfr[p][nj] = *(const short8v*)&Ws[p][(wn + nj * 16 + lr) * 40 + lg * 8];
#pragma unroll
        for (int mi = 0; mi < 4; ++mi) {
            short8v a0 = *(const short8v*)&As[0][(wm + mi * 16 + lr) * 40 + lg * 8];
            short8v a1 = *(const short8v*)&As[1][(wm + mi * 16 + lr) * 40 + lg * 8];
            short8v a2 = *(const short8v*)&As[2][(wm + mi * 16 + lr) * 40 + lg * 8];
#pragma unroll
            for (int nj = 0; nj < 4; ++nj) {
                f32x4 c = acc[mi][nj];
                c = __builtin_amdgcn_mfma_f32_16x16x32_bf16(a2, bfr[1][nj], c, 0, 0, 0);
                c = __builtin_amdgcn_mfma_f32_16x16x32_bf16(a1, bfr[2][nj], c, 0, 0, 0);
                c = __builtin_amdgcn_mfma_f32_16x16x32_bf16(a1, bfr[1][nj], c, 0, 0, 0);
                c = __builtin_amdgcn_mfma_f32_16x16x32_bf16(a2, bfr[0][nj], c, 0, 0, 0);
                c = __builtin_amdgcn_mfma_f32_16x16x32_bf16(a0, bfr[2][nj], c, 0, 0, 0);
                c = __builtin_amdgcn_mfma_f32_16x16x32_bf16(a1, bfr[0][nj], c, 0, 0, 0);
                c = __builtin_amdgcn_mfma_f32_16x16x32_bf16(a0, bfr[1][nj], c, 0, 0, 0);
                c = __builtin_amdgcn_mfma_f32_16x16x32_bf16(a0, bfr[0][nj], c, 0, 0, 0);
                acc[mi][nj] = c;
            }
        }
        __syncthreads();
    }
#pragma unroll
    for (int mi = 0; mi < 4; ++mi)
#pragma unroll
        for (int nj = 0; nj < 4; ++nj)
#pragma unroll
            for (int r = 0; r < 4; ++r) {
                int m = bm + wm + mi * 16 + lg * 4 + r;
                int n = bn + wn + nj * 16 + lr;
                float v = acc[mi][nj][r] + bias[n];
                if (EPI == 0) {
                    Cf[(size_t)m * N + n] = v;
                } else {
                    Split3 sp = split3(v);
                    S0[(size_t)m * N + n] = sp.b0;
                    S1[(size_t)m * N + n] = sp.b1;
                    S2[(size_t)m * N + n] = sp.b2;
                }
            }
}

template<int K>
__global__ __launch_bounds__(256)
void gemm8_k(const unsigned short* __restrict__ A0, const unsigned short* __restrict__ A1,
             const unsigned short* __restrict__ A2,
             const unsigned short* __restrict__ W0, const unsigned short* __restrict__ W1,
             const unsigned short* __restrict__ W2,
             const float* __restrict__ bias, float* __restrict__ C, int N)
{
    __shared__ short As[3][128 * 40];
    __shared__ short Ws[3][128 * 40];
    gemm8_body<K, 0>(A0, A1, A2, W0, W1, W2, bias, C, nullptr, nullptr, nullptr, N, As, Ws);
}

struct G8 { const unsigned short *A0, *A1, *A2, *W0, *W1, *W2; const float* bias;
            float* Cf; unsigned short *S0, *S1, *S2; };

template<int K, int EPI>
__global__ __launch_bounds__(256)
void gemm8pair_k(G8 ga, G8 gb, int N)
{
    __shared__ short As[3][128 * 40];
    __shared__ short Ws[3][128 * 40];
    const G8& g = (blockIdx.z == 0) ? ga : gb;
    gemm8_body<K, EPI>(g.A0, g.A1, g.A2, g.W0, g.W1, g.W2, g.bias, g.Cf,
                       g.S0, g.S1, g.S2, N, As, Ws);
}

// ---------------- bf16 MFMA GEMM (decoder): C = A@W^T + bias ----------------------------
template<int K, int EPI>
__global__ __launch_bounds__(256)
void gemmbf_k(const short* __restrict__ A, const short* __restrict__ W,
              const float* __restrict__ bias, float* __restrict__ C, int N,
              unsigned short* __restrict__ Cb,
              const float* __restrict__ escale, const float* __restrict__ eshift)
{
    __shared__ short As[128 * 40];
    __shared__ short Ws[128 * 40];
    const int t = threadIdx.x;
    const int bm = blockIdx.x << 7, bn = blockIdx.y << 7;   // x = M (fast)
    const int lane = t & 63, wid = t >> 6;
    const int wm = (wid >> 1) << 6, wn = (wid & 1) << 6;
    const int lr = lane & 15, lg = lane >> 4;
    f32x4 acc[4][4] = {};
    for (int k0 = 0; k0 < K; k0 += 32) {
#pragma unroll
        for (int s = 0; s < 2; ++s) {
            int c = t + (s << 8);
            int row = c >> 2, kc = (c & 3) << 3;
            *(short8v*)&As[row * 40 + kc] = *(const short8v*)(A + (size_t)(bm + row) * K + k0 + kc);
            *(short8v*)&Ws[row * 40 + kc] = *(const short8v*)(W + (size_t)(bn + row) * K + k0 + kc);
        }
        __syncthreads();
        short8v af[4], bf[4];
#pragma unroll
        for (int mi = 0; mi < 4; ++mi) af[mi] = *(const short8v*)&As[(wm + mi * 16 + lr) * 40 + lg * 8];
#pragma unroll
        for (int nj = 0; nj < 4; ++nj) bf[nj] = *(const short8v*)&Ws[(wn + nj * 16 + lr) * 40 + lg * 8];
#pragma unroll
        for (int mi = 0; mi < 4; ++mi)
#pragma unroll
            for (int nj = 0; nj < 4; ++nj)
                acc[mi][nj] = __builtin_amdgcn_mfma_f32_16x16x32_bf16(af[mi], bf[nj], acc[mi][nj], 0, 0, 0);
        __syncthreads();
    }
#pragma unroll
    for (int mi = 0; mi < 4; ++mi)
#pragma unroll
        for (int nj = 0; nj < 4; ++nj)
#pragma unroll
            for (int r = 0; r < 4; ++r) {
                int m = bm + wm + mi * 16 + lg * 4 + r;
                int n = bn + wn + nj * 16 + lr;
                float v = acc[mi][nj][r] + bias[n];
                if (EPI == 2) v = escale[n] * v + eshift[n];
                C[(size_t)m * N + n] = v;
                if (EPI == 1) Cb[(size_t)m * N + n] = f2bf(v);
            }
}

// -------------- merged preprocessing: weight splits, input splits, dec cvts, c2/cbS -----
// w1b/wrb/w2b live in FRESH workspace past cbS2 (no alias with encoder state) -> safe at t=0.
__global__ __launch_bounds__(256)
void pre_k(const float* __restrict__ x, const float* __restrict__ scale,
           const float* __restrict__ shift,
           unsigned short* __restrict__ x0, unsigned short* __restrict__ x1,
           unsigned short* __restrict__ x2,
           const float* __restrict__ a,
           unsigned short* __restrict__ a0, unsigned short* __restrict__ a1,
           unsigned short* __restrict__ a2,
           const float* __restrict__ ain_w, const float* __restrict__ win_w,
           const float* __restrict__ ares_w, const float* __restrict__ wres_w,
           const float* __restrict__ out_w, unsigned short* __restrict__ wsb,
           const float* __restrict__ dec1_w, const float* __restrict__ dres_w,
           const float* __restrict__ dec2_w,
           unsigned short* __restrict__ w1b, unsigned short* __restrict__ wrb,
           unsigned short* __restrict__ w2b,
           const float* __restrict__ cb, float* __restrict__ c2, int* __restrict__ counts,
           unsigned short* __restrict__ cbS0, unsigned short* __restrict__ cbS1,
           unsigned short* __restrict__ cbS2)
{
    const int b = blockIdx.x;
    const int t = threadIdx.x;
    if (b < 768) {                                   // encoder weight splits
        int g4 = b * 256 + t;
        const float* src; unsigned short *d0, *d1, *d2; int base;
        if (g4 < 16384)       { src = ain_w;  d0 = wsb;           d1 = wsb + 65536;   d2 = wsb + 131072;  base = 0; }
        else if (g4 < 32768)  { src = win_w;  d0 = wsb + 196608;  d1 = wsb + 262144;  d2 = wsb + 327680;  base = 16384; }
        else if (g4 < 98304)  { src = ares_w; d0 = wsb + 393216;  d1 = wsb + 655360;  d2 = wsb + 917504;  base = 32768; }
        else if (g4 < 163840) { src = wres_w; d0 = wsb + 1179648; d1 = wsb + 1441792; d2 = wsb + 1703936; base = 98304; }
        else                  { src = out_w;  d0 = wsb + 1966080; d1 = wsb + 2097152; d2 = wsb + 2228224; base = 163840; }
        int l4 = g4 - base;
        float4 v = *(const float4*)(src + (size_t)l4 * 4);
        float vals[4] = {v.x, v.y, v.z, v.w};
        ushort4v o0, o1, o2;
#pragma unroll
        for (int i = 0; i < 4; ++i) {
            Split3 s = split3(vals[i]);
            o0[i] = s.b0; o1[i] = s.b1; o2[i] = s.b2;
        }
        *(ushort4v*)(d0 + (size_t)l4 * 4) = o0;
        *(ushort4v*)(d1 + (size_t)l4 * 4) = o1;
        *(ushort4v*)(d2 + (size_t)l4 * 4) = o2;
    } else if (b < 4864) {                           // x->xs splits, a splits
        int bb = b - 768;
        if (bb < 2048) {
            int g = bb * 256 + t;
            float4 v = *(const float4*)(x + (size_t)g * 4);
            int col = (g * 4) & (IND - 1);
            float vals[4] = {v.x, v.y, v.z, v.w};
            ushort4v o0, o1, o2;
#pragma unroll
            for (int i = 0; i < 4; ++i) {
                float xs = (vals[i] - shift[col + i]) / scale[col + i];
                Split3 s = split3(xs);
                o0[i] = s.b0; o1[i] = s.b1; o2[i] = s.b2;
            }
            *(ushort4v*)(x0 + (size_t)g * 4) = o0;
            *(ushort4v*)(x1 + (size_t)g * 4) = o1;
            *(ushort4v*)(x2 + (size_t)g * 4) = o2;
        } else {
            int g = (bb - 2048) * 256 + t;
            float4 v = *(const float4*)(a + (size_t)g * 4);
            float vals[4] = {v.x, v.y, v.z, v.w};
            ushort4v o0, o1, o2;
#pragma unroll
            for (int i = 0; i < 4; ++i) {
                Split3 s = split3(vals[i]);
                o0[i] = s.b0; o1[i] = s.b1; o2[i] = s.b2;
            }
            *(ushort4v*)(a0 + (size_t)g * 4) = o0;
            *(ushort4v*)(a1 + (size_t)g * 4) = o1;
            *(ushort4v*)(a2 + (size_t)g * 4) = o2;
        }
    } else if (b < 6656) {                           // decoder weight cvts (fresh buffers)
        int g = (b - 4864) * 256 + t;
        if (g < 131072)       w1b[g] = f2bf(dec1_w[g]);
        else if (g < 393216)  wrb[g - 131072] = f2bf(dres_w[g - 131072]);
        else if (g < 458752)  w2b[g - 393216] = f2bf(dec2_w[g - 393216]);
    } else {                                         // codebook: c2, counts, split planes
        int j = (b - 6656) * 256 + t;
        if (j < NE) {
            float s = 0.f;
            const float* p = cb + (size_t)j * ED;
#pragma unroll
            for (int d = 0; d < ED; ++d) s = fmaf(p[d], p[d], s);
            c2[j] = s;
            counts[j] = 0;
#pragma unroll
            for (int dc = 0; dc < 64; dc += 4) {
                float4 v = *(const float4*)(p + dc);
                float vals[4] = {v.x, v.y, v.z, v.w};
                ushort4v o0, o1, o2;
#pragma unroll
                for (int i = 0; i < 4; ++i) {
                    Split3 sp = split3(vals[i]);
                    o0[i] = sp.b0; o1[i] = sp.b1; o2[i] = sp.b2;
                }
                *(ushort4v*)(cbS0 + (size_t)j * 64 + dc) = o0;
                *(ushort4v*)(cbS1 + (size_t)j * 64 + dc) = o1;
                *(ushort4v*)(cbS2 + (size_t)j * 64 + dc) = o2;
            }
        }
    }
}

// -------------- fused encoder resblock tail on split state ------------------------------
__global__ __launch_bounds__(256)
void ln_enc2s_k(const float* __restrict__ T1, const float* __restrict__ T2,
                unsigned short* __restrict__ a0, unsigned short* __restrict__ a1,
                unsigned short* __restrict__ a2,
                unsigned short* __restrict__ h0, unsigned short* __restrict__ h1,
                unsigned short* __restrict__ h2,
                const float* __restrict__ ag, const float* __restrict__ abe,
                const float* __restrict__ wg, const float* __restrict__ wbe)
{
    const int lane = threadIdx.x & 63;
    const int row  = (blockIdx.x << 2) + (threadIdx.x >> 6);
    const int col  = lane << 3;
    const size_t base = (size_t)row * DE + col;
    float t[8];
    { float4 p0 = *(const float4*)(T1 + base); float4 p1 = *(const float4*)(T1 + base + 4);
      t[0]=p0.x; t[1]=p0.y; t[2]=p0.z; t[3]=p0.w; t[4]=p1.x; t[5]=p1.y; t[6]=p1.z; t[7]=p1.w; }
    float s = 0.f;
#pragma unroll
    for (int i = 0; i < 8; ++i) s += t[i];
    s = wave_sum(s);
    float mean = s * (1.0f / 512.0f);
    float vs = 0.f;
#pragma unroll
    for (int i = 0; i < 8; ++i) { float d = t[i] - mean; vs += d * d; }
    vs = wave_sum(vs);
    float rstd = 1.0f / sqrtf(vs * (1.0f / 512.0f) + 1e-5f);
    float avn[8];
    {
        ushort8v b0 = *(const ushort8v*)(a0 + base);
        ushort8v b1 = *(const ushort8v*)(a1 + base);
        ushort8v b2 = *(const ushort8v*)(a2 + base);
        ushort8v o0, o1, o2;
#pragma unroll
        for (int i = 0; i < 8; ++i) {
            float avv = bf2f(b0[i]) + bf2f(b1[i]) + bf2f(b2[i]);
            float lnv = (t[i] - mean) * rstd * ag[col + i] + abe[col + i];
            avn[i] = avv + fmaxf(lnv, 0.0f);
            Split3 sp = split3(avn[i]);
            o0[i] = sp.b0; o1[i] = sp.b1; o2[i] = sp.b2;
        }
        *(ushort8v*)(a0 + base) = o0;
        *(ushort8v*)(a1 + base) = o1;
        *(ushort8v*)(a2 + base) = o2;
    }
    { float4 p0 = *(const float4*)(T2 + base); float4 p1 = *(const float4*)(T2 + base + 4);
      t[0]=p0.x; t[1]=p0.y; t[2]=p0.z; t[3]=p0.w; t[4]=p1.x; t[5]=p1.y; t[6]=p1.z; t[7]=p1.w; }
    s = 0.f;
#pragma unroll
    for (int i = 0; i < 8; ++i) s += t[i];
    s = wave_sum(s);
    float mean2 = s * (1.0f / 512.0f);
    vs = 0.f;
#pragma unroll
    for (int i = 0; i < 8; ++i) { float d = t[i] - mean2; vs += d * d; }
    vs = wave_sum(vs);
    float rstd2 = 1.0f / sqrtf(vs * (1.0f / 512.0f) + 1e-5f);
    {
        ushort8v b0 = *(const ushort8v*)(h0 + base);
        ushort8v b1 = *(const ushort8v*)(h1 + base);
        ushort8v b2 = *(const ushort8v*)(h2 + base);
        ushort8v o0, o1, o2;
#pragma unroll
        for (int i = 0; i < 8; ++i) {
            float hv  = bf2f(b0[i]) + bf2f(b1[i]) + bf2f(b2[i]);
            float lnv = (t[i] - mean2) * rstd2 * wg[col + i] + wbe[col + i];
            float hn  = (hv + fmaxf(lnv, 0.0f)) * avn[i];
            Split3 sp = split3(hn);
            o0[i] = sp.b0; o1[i] = sp.b1; o2[i] = sp.b2;
        }
        *(ushort8v*)(h0 + base) = o0;
        *(ushort8v*)(h1 + base) = o1;
        *(ushort8v*)(h2 + base) = o2;
    }
}

// -------------- decoder resblock tail ---------------------------------------------------
__global__ __launch_bounds__(256)
void ln_dec_k(const float* __restrict__ t_, float* __restrict__ h,
              const float* __restrict__ g, const float* __restrict__ be,
              unsigned short* __restrict__ hb)
{
    const int lane = threadIdx.x & 63;
    const int row  = (blockIdx.x << 2) + (threadIdx.x >> 6);
    const int col  = lane << 3;
    const size_t base = (size_t)row * DE + col;
    float t[8];
    { float4 p0 = *(const float4*)(t_ + base); float4 p1 = *(const float4*)(t_ + base + 4);
      t[0]=p0.x; t[1]=p0.y; t[2]=p0.z; t[3]=p0.w; t[4]=p1.x; t[5]=p1.y; t[6]=p1.z; t[7]=p1.w; }
    float s = 0.f;
#pragma unroll
    for (int i = 0; i < 8; ++i) s += t[i];
    s = wave_sum(s);
    float mean = s * (1.0f / 512.0f);
    float vs = 0.f;
#pragma unroll
    for (int i = 0; i < 8; ++i) { float d = t[i] - mean; vs += d * d; }
    vs = wave_sum(vs);
    float rstd = 1.0f / sqrtf(vs * (1.0f / 512.0f) + 1e-5f);
    float4 p0 = *(const float4*)(h + base); float4 p1 = *(const float4*)(h + base + 4);
    float hv[8] = {p0.x,p0.y,p0.z,p0.w,p1.x,p1.y,p1.z,p1.w};
    float hn[8];
    ushort8v ob;
#pragma unroll
    for (int i = 0; i < 8; ++i) {
        float lnv = (t[i] - mean) * rstd * g[col + i] + be[col + i];
        hn[i] = hv[i] + fmaxf(lnv, 0.0f);
        ob[i] = f2bf(hn[i]);
    }
    float4 o0 = {hn[0],hn[1],hn[2],hn[3]}, o1 = {hn[4],hn[5],hn[6],hn[7]};
    *(float4*)(h + base) = o0; *(float4*)(h + base + 4) = o1;
    *(ushort8v*)(hb + base) = ob;
}

// -------------- VQ v7: MFMA distances, double-buffered code tiles (T14 split) -----------
__global__ __launch_bounds__(256)
void vq_k(const float* __restrict__ ze, const float* __restrict__ cb, const float* __restrict__ c2,
          const unsigned short* __restrict__ cbS0, const unsigned short* __restrict__ cbS1,
          const unsigned short* __restrict__ cbS2,
          float* __restrict__ idx_dst, float* __restrict__ zst_dst,
          unsigned short* __restrict__ zb,
          int* __restrict__ counts, float* __restrict__ partials)
{
    __shared__ unsigned short P[2][3][64 * 64];
    __shared__ float z2s[64];
    __shared__ int   bidxs[64];
    __shared__ float red[4];
    const int t = threadIdx.x;
    const int lane = t & 63, w = t >> 6;
    const size_t row0 = (size_t)blockIdx.x * 64;

#pragma unroll
    for (int s = 0; s < 2; ++s) {
        int c = t + (s << 8);
        int row = c >> 3, kb = c & 7;
        float4 v0 = *(const float4*)(ze + (row0 + row) * 64 + kb * 8);
        float4 v1 = *(const float4*)(ze + (row0 + row) * 64 + kb * 8 + 4);
        float vals[8] = {v0.x, v0.y, v0.z, v0.w, v1.x, v1.y, v1.z, v1.w};
        ushort8v o0, o1, o2;
#pragma unroll
        for (int i = 0; i < 8; ++i) {
            Split3 sp = split3(vals[i]);
            o0[i] = sp.b0; o1[i] = sp.b1; o2[i] = sp.b2;
        }
        int base = row * 64 + ((kb ^ (row & 7)) << 3);
        *(ushort8v*)&P[1][0][base] = o0;
        *(ushort8v*)&P[1][1][base] = o1;
        *(ushort8v*)&P[1][2][base] = o2;
        int gbase = row * 64 + kb * 8;
        *(ushort8v*)&P[0][0][base] = *(const ushort8v*)(cbS0 + gbase);
        *(ushort8v*)&P[0][1][base] = *(const ushort8v*)(cbS1 + gbase);
        *(ushort8v*)&P[0][2][base] = *(const ushort8v*)(cbS2 + gbase);
    }
    if (t < 64) {
        float z2 = 0.f;
        const float* zp = ze + (row0 + t) * 64;
#pragma unroll 8
        for (int d = 0; d < 64; ++d) z2 = fmaf(zp[d], zp[d], z2);
        z2s[t] = z2;
    }
    __syncthreads();

    short8v af[2][3];
    {
        int row = (w << 4) + (lane & 15);
#pragma unroll
        for (int ks = 0; ks < 2; ++ks) {
            int kb = (lane >> 4) + ks * 4;
            int base = row * 64 + ((kb ^ (row & 7)) << 3);
#pragma unroll
            for (int p = 0; p < 3; ++p)
                af[ks][p] = *(const short8v*)&P[1][p][base];
        }
    }
    __syncthreads();

    float best[4] = {INFINITY, INFINITY, INFINITY, INFINITY};
    int   bid[4]  = {0, 0, 0, 0};
    for (int tt = 0; tt < 16; ++tt) {
        const int cur = tt & 1;
        ushort8v nx0[2], nx1[2], nx2[2];
        if (tt < 15) {
#pragma unroll
            for (int s = 0; s < 2; ++s) {
                int c = t + (s << 8);
                int code = c >> 3, kb = c & 7;
                size_t gbase = (size_t)((tt + 1) * 64 + code) * 64 + kb * 8;
                nx0[s] = *(const ushort8v*)(cbS0 + gbase);
                nx1[s] = *(const ushort8v*)(cbS1 + gbase);
                nx2[s] = *(const ushort8v*)(cbS2 + gbase);
            }
        }
        const int t0 = tt << 6;
#pragma unroll
        for (int ct = 0; ct < 4; ++ct) {
            f32x4 acc = {0.f, 0.f, 0.f, 0.f};
            int code = (ct << 4) + (lane & 15);
#pragma unroll
            for (int ks = 0; ks < 2; ++ks) {
                int kb = (lane >> 4) + ks * 4;
                int base = code * 64 + ((kb ^ (code & 7)) << 3);
                short8v b0 = *(const short8v*)&P[cur][0][base];
                short8v b1 = *(const short8v*)&P[cur][1][base];
                short8v b2 = *(const short8v*)&P[cur][2][base];
                acc = __builtin_amdgcn_mfma_f32_16x16x32_bf16(af[ks][2], b1, acc, 0, 0, 0);
                acc = __builtin_amdgcn_mfma_f32_16x16x32_bf16(af[ks][1], b2, acc, 0, 0, 0);
                acc = __builtin_amdgcn_mfma_f32_16x16x32_bf16(af[ks][1], b1, acc, 0, 0, 0);
                acc = __builtin_amdgcn_mfma_f32_16x16x32_bf16(af[ks][2], b0, acc, 0, 0, 0);
                acc = __builtin_amdgcn_mfma_f32_16x16x32_bf16(af[ks][0], b2, acc, 0, 0, 0);
                acc = __builtin_amdgcn_mfma_f32_16x16x32_bf16(af[ks][1], b0, acc, 0, 0, 0);
                acc = __builtin_amdgcn_mfma_f32_16x16x32_bf16(af[ks][0], b1, acc, 0, 0, 0);
                acc = __builtin_amdgcn_mfma_f32_16x16x32_bf16(af[ks][0], b0, acc, 0, 0, 0);
            }
            float c2v = c2[t0 + code];
            int gcode = t0 + code;
#pragma unroll
            for (int r = 0; r < 4; ++r) {
                float z2v = z2s[(w << 4) + ((lane >> 4) << 2) + r];
                float term = __fadd_rn(z2v, c2v);
                float dist = __fsub_rn(term, __fmul_rn(2.0f, acc[r]));
                if (dist < best[r]) { best[r] = dist; bid[r] = gcode; }
            }
        }
        if (tt < 15) {
#pragma unroll
            for (int s = 0; s < 2; ++s) {
                int c = t + (s << 8);
                int code = c >> 3, kb = c & 7;
                int base = code * 64 + ((kb ^ (code & 7)) << 3);
                *(ushort8v*)&P[cur ^ 1][0][base] = nx0[s];
                *(ushort8v*)&P[cur ^ 1][1][base] = nx1[s];
                *(ushort8v*)&P[cur ^ 1][2][base] = nx2[s];
            }
        }
        __syncthreads();
    }
#pragma unroll
    for (int r = 0; r < 4; ++r) {
        float bd = best[r]; int bi = bid[r];
#pragma unroll
        for (int m = 1; m < 16; m <<= 1) {
            float od = __shfl_xor(bd, m, 64);
            int   oi = __shfl_xor(bi, m, 64);
            if (od < bd || (od == bd && oi < bi)) { bd = od; bi = oi; }
        }
        if ((lane & 15) == 0) {
            int row = (w << 4) + ((lane >> 4) << 2) + r;
            bidxs[row] = bi;
            idx_dst[row0 + row] = (float)bi;
            atomicAdd(&counts[bi], 1);
        }
    }
    __syncthreads();
    const int row = t >> 2, cq = t & 3;
    const int bi = bidxs[row];
    float lsum = 0.f;
#pragma unroll
    for (int dd = 0; dd < 16; dd += 4) {
        int d0 = (cq << 4) + dd;
        float4 q4 = *(const float4*)(cb + (size_t)bi * 64 + d0);
        float qv[4] = {q4.x, q4.y, q4.z, q4.w};
        float4 zv4 = *(const float4*)(ze + (row0 + row) * 64 + d0);
        float zvv[4] = {zv4.x, zv4.y, zv4.z, zv4.w};
        float zst[4];
#pragma unroll
        for (int i = 0; i < 4; ++i) {
            float zv = zvv[i];
            float df = qv[i] - zv;
            lsum = fmaf(df, df, lsum);
            zst[i] = __fadd_rn(zv, __fsub_rn(qv[i], zv));
            zb[(row0 + row) * 64 + d0 + i] = f2bf(zst[i]);
        }
        float2 o0 = {zst[0], zst[1]}, o1 = {zst[2], zst[3]};
        *(float2*)(zst_dst + (row0 + row) * 64 + d0) = o0;
        *(float2*)(zst_dst + (row0 + row) * 64 + d0 + 2) = o1;
    }
    lsum = wave_sum(lsum);
    if ((t & 63) == 0) red[t >> 6] = lsum;
    __syncthreads();
    if (t == 0) partials[blockIdx.x] = ((red[0] + red[1]) + red[2]) + red[3];
}

// -------------- finalize: loss + perplexity ---------------------------------------------
__global__ __launch_bounds__(256)
void fin_k(const float* __restrict__ partials, const int* __restrict__ counts,
           float* __restrict__ loss_out, float* __restrict__ perp_out)
{
    __shared__ float red[4];
    __shared__ float red2[4];
    const int tid = threadIdx.x;
    float v = 0.f;
    for (int c = tid; c < 1024; c += 256) v += partials[c];
    float s = wave_sum(v);
    if ((tid & 63) == 0) red[tid >> 6] = s;
    float ep = 0.f;
    for (int c = tid; c < NE; c += 256) {
        float e = (float)counts[c] * (1.0f / 65536.0f);
        ep += e * logf(e + 1e-10f);
    }
    ep = wave_sum(ep);
    if ((tid & 63) == 0) red2[tid >> 6] = ep;
    __syncthreads();
    if (tid == 0) {
        float S = ((red[0] + red[1]) + red[2]) + red[3];
        float E = ((red2[0] + red2[1]) + red2[2]) + red2[3];
        loss_out[0] = 1.25f * (S * (1.0f / 4194304.0f));
        perp_out[0] = expf(-E);
    }
}

extern "C" void kernel_launch(void* const* d_in, const int* in_sizes, int n_in,
                              void* d_out, int out_size, void* d_ws, size_t ws_size,
                              hipStream_t stream)
{
    const float* x       = (const float*)d_in[0];
    const float* a       = (const float*)d_in[1];
    const float* scale   = (const float*)d_in[2];
    const float* shift   = (const float*)d_in[3];
    const float* win_w   = (const float*)d_in[4];
    const float* win_b   = (const float*)d_in[5];
    const float* ain_w   = (const float*)d_in[6];
    const float* ain_b   = (const float*)d_in[7];
    const float* wres_w  = (const float*)d_in[8];
    const float* wres_b  = (const float*)d_in[9];
    const float* wres_g  = (const float*)d_in[10];
    const float* wres_be = (const float*)d_in[11];
    const float* ares_w  = (const float*)d_in[12];
    const float* ares_b  = (const float*)d_in[13];
    const float* ares_g  = (const float*)d_in[14];
    const float* ares_be = (const float*)d_in[15];
    const float* out_w   = (const float*)d_in[16];
    const float* out_b   = (const float*)d_in[17];
    const float* dec1_w  = (const float*)d_in[18];
    const float* dec1_b  = (const float*)d_in[19];
    const float* dres_w  = (const float*)d_in[20];
    const float* dres_b  = (const float*)d_in[21];
    const float* dres_g  = (const float*)d_in[22];
    const float* dres_be = (const float*)d_in[23];
    const float* dec2_w  = (const float*)d_in[24];
    const float* dec2_b  = (const float*)d_in[25];
    const float* cb      = (const float*)d_in[26];

    float* ws = (float*)d_ws;
    unsigned short* u = (unsigned short*)d_ws;
    unsigned short* avS0 = u;
    unsigned short* avS1 = u + 8388608;
    unsigned short* avS2 = u + 16777216;
    unsigned short* hS0  = u + 25165824;
    unsigned short* hS1  = u + 33554432;
    unsigned short* hS2  = u + 41943040;
    float* T1 = ws + 25165824;
    float* T2 = ws + 29360128;
    float* ZE = ws + 25165824;
    unsigned short* aS0  = u + 50331648, *aS1  = u + 52428800, *aS2  = u + 54525952;
    unsigned short* xsS0 = u + 56623104, *xsS1 = u + 58720256, *xsS2 = u + 60817408;
    unsigned short* ZB  = u;
    float* t_dec = ws + 4194304;
    float* hd    = ws + 12582912;
    unsigned short* Hb = (unsigned short*)(ws + 29360128);
    unsigned short* wsb = u + 67108864;
    unsigned short* ainS0 = wsb,            *ainS1 = wsb + 65536,  *ainS2 = wsb + 131072;
    unsigned short* winS0 = wsb + 196608,   *winS1 = wsb + 262144, *winS2 = wsb + 327680;
    unsigned short* areS0 = wsb + 393216,   *areS1 = wsb + 655360, *areS2 = wsb + 917504;
    unsigned short* wreS0 = wsb + 1179648,  *wreS1 = wsb + 1441792,*wreS2 = wsb + 1703936;
    unsigned short* outS0 = wsb + 1966080,  *outS1 = wsb + 2097152,*outS2 = wsb + 2228224;
    float* c2v      = ws + 34800000;
    int*   counts   = (int*)(ws + 34801024);
    float* partials = ws + 34802048;
    unsigned short* cbS0 = u + 69606144;
    unsigned short* cbS1 = u + 69671680;
    unsigned short* cbS2 = u + 69737216;
    // decoder bf16 weights: FRESH region past cbS2 (no alias; ~140.5 MB total, < proven cap)
    unsigned short* w1b = u + 69802752;   // 131072
    unsigned short* wrb = u + 69933824;   // 262144
    unsigned short* w2b = u + 70195968;   // 65536

    float* dout = (float*)d_out;

    pre_k<<<6660, 256, 0, stream>>>(x, scale, shift, xsS0, xsS1, xsS2,
                                    a, aS0, aS1, aS2,
                                    ain_w, win_w, ares_w, wres_w, out_w, wsb,
                                    dec1_w, dres_w, dec2_w, w1b, wrb, w2b,
                                    cb, c2v, counts, cbS0, cbS1, cbS2);
    {
        G8 ga = {aS0, aS1, aS2, ainS0, ainS1, ainS2, ain_b, nullptr, avS0, avS1, avS2};
        G8 gb = {xsS0, xsS1, xsS2, winS0, winS1, winS2, win_b, nullptr, hS0, hS1, hS2};
        gemm8pair_k<128, 1><<<dim3(128, 4, 2), 256, 0, stream>>>(ga, gb, DE);
    }
    for (int r = 0; r < 3; ++r) {
        for (int half = 0; half < 2; ++half) {
            const size_t mo = (size_t)half * 8192 * DE;
            G8 ga = {avS0 + mo, avS1 + mo, avS2 + mo, areS0, areS1, areS2, ares_b, T1, nullptr, nullptr, nullptr};
            G8 gb = {hS0 + mo,  hS1 + mo,  hS2 + mo,  wreS0, wreS1, wreS2, wres_b, T2, nullptr, nullptr, nullptr};
            gemm8pair_k<512, 0><<<dim3(64, 4, 2), 256, 0, stream>>>(ga, gb, DE);
            ln_enc2s_k<<<2048, 256, 0, stream>>>(T1, T2,
                avS0 + mo, avS1 + mo, avS2 + mo, hS0 + mo, hS1 + mo, hS2 + mo,
                ares_g, ares_be, wres_g, wres_be);
        }
    }
    gemm8_k<512><<<dim3(128, 2), 256, 0, stream>>>(hS0, hS1, hS2, outS0, outS1, outS2, out_b, ZE, DOUTD);
    vq_k<<<1024, 256, 0, stream>>>(ZE, cb, c2v, cbS0, cbS1, cbS2,
                                   dout + O_IDX, dout + O_ZQ, ZB, counts, partials);
    fin_k<<<1, 256, 0, stream>>>(partials, counts, dout, dout + O_PERP);
    gemmbf_k<256, 1><<<dim3(128, 4), 256, 0, stream>>>(
        (const short*)ZB, (const short*)w1b, dec1_b, hd, DE, Hb, nullptr, nullptr);
    for (int r = 0; r < 3; ++r) {
        gemmbf_k<512, 0><<<dim3(128, 4), 256, 0, stream>>>(
            (const short*)Hb, (const short*)wrb, dres_b, t_dec, DE, nullptr, nullptr, nullptr);
        ln_dec_k<<<4096, 256, 0, stream>>>(t_dec, hd, dres_g, dres_be, Hb);
    }
    gemmbf_k<512, 2><<<dim3(128, 1), 256, 0, stream>>>(
        (const short*)Hb, (const short*)w2b, dec2_b, dout + O_XHAT, IND, nullptr, scale, shift);
}